// Round 10
// baseline (8845.226 us; speedup 1.0000x reference)
//
#include <hip/hip_runtime.h>
#include <hip/hip_bf16.h>
#include <cstdint>
#include <cstddef>

#define DEVI __device__ __forceinline__

// ---------- constants ----------
#define BB 128
#define TT 30
#define VOCAB 10000
#define ENCD 2048
#define NPIX 49
#define SLOT 65536   // 128*512 elements

typedef __attribute__((ext_vector_type(8))) short bf16x8;
typedef __attribute__((ext_vector_type(4))) float f32x4;

DEVI float bf2f(unsigned short u){ union{float f; unsigned int i;} x; x.i=((unsigned)u)<<16; return x.f; }
DEVI unsigned short f2bf(float f){ union{float f; unsigned int i;} x; x.f=f; unsigned r=x.i + 0x7fffu + ((x.i>>16)&1u); return (unsigned short)(r>>16); }
DEVI float sigm(float x){ return 1.0f/(1.0f+expf(-x)); }
DEVI f32x4 mfma16(bf16x8 a, bf16x8 b, f32x4 c){ return __builtin_amdgcn_mfma_f32_16x16x32_bf16(a,b,c,0,0,0); }

// ---------- coherence-point (bypass) loads/stores ----------
DEVI uint4 byp16(const void* p){
  const unsigned long long* q=(const unsigned long long*)p;
  unsigned long long a=__hip_atomic_load(q,   __ATOMIC_RELAXED, __HIP_MEMORY_SCOPE_AGENT);
  unsigned long long b=__hip_atomic_load(q+1, __ATOMIC_RELAXED, __HIP_MEMORY_SCOPE_AGENT);
  uint4 r; r.x=(unsigned)a; r.y=(unsigned)(a>>32); r.z=(unsigned)b; r.w=(unsigned)(b>>32); return r;
}
DEVI unsigned byp4(const void* p){
  return __hip_atomic_load((const unsigned*)p, __ATOMIC_RELAXED, __HIP_MEMORY_SCOPE_AGENT);
}
DEVI void byps4(unsigned short* p, unsigned v){
  __hip_atomic_store((unsigned*)p, v, __ATOMIC_RELAXED, __HIP_MEMORY_SCOPE_AGENT);
}

// ---------- fence-free sync: flags at 64B stride ----------
DEVI void waitarr(int* base, int n, int thresh){
  __syncthreads();
  if(threadIdx.x < 64){
    for(;;){
      int v = (threadIdx.x<n) ? __hip_atomic_load(base + threadIdx.x*16, __ATOMIC_RELAXED, __HIP_MEMORY_SCOPE_AGENT)
                              : 0x7fffffff;
      if(__all(v >= thresh)) break;
      __builtin_amdgcn_s_sleep(8);
    }
  }
  asm volatile("" ::: "memory");
  __syncthreads();
}
DEVI void setflag(int* f, int val){
  __syncthreads();   // drains vmcnt: block's bypass stores complete at coherence point
  if(threadIdx.x==0) __hip_atomic_store(f, val, __ATOMIC_RELAXED, __HIP_MEMORY_SCOPE_AGENT);
}

// ---------- sort: stable descending by length ----------
__global__ void k_sort(const int* __restrict__ lens, int* __restrict__ order, int* __restrict__ Bt){
  __shared__ int L[BB];
  int i = threadIdx.x;
  L[i] = lens[i];
  __syncthreads();
  int li = L[i]; int rank = 0;
  for(int j=0;j<BB;j++){ int lj=L[j]; rank += (lj>li) || (lj==li && j<i); }
  order[rank] = i;
  if(i<TT){ int c=0; for(int j=0;j<BB;j++) c += (L[j]>i); Bt[i]=c; }
}

// ---------- weight f32 -> bf16 conversion ----------
struct WC13 { const float* src[13]; unsigned short* dst[13]; int n[13]; };
__global__ void k_wconv(WC13 wc){
  int stride = gridDim.x*blockDim.x;
  int tid0 = blockIdx.x*blockDim.x + threadIdx.x;
  for(int s=0;s<13;s++){
    const float4* src=(const float4*)wc.src[s];
    int n4 = wc.n[s]>>2;
    ushort4* dst=(ushort4*)wc.dst[s];
    for(int i=tid0;i<n4;i+=stride){
      float4 v=src[i];
      ushort4 o; o.x=f2bf(v.x); o.y=f2bf(v.y); o.z=f2bf(v.z); o.w=f2bf(v.w);
      dst[i]=o;
    }
  }
}

// ---------- xt build ----------
__global__ void k_xt(const int* __restrict__ caps, const int* __restrict__ order,
                     const float* __restrict__ embW, const unsigned short* __restrict__ gimg,
                     unsigned short* __restrict__ xt){
  int total=BB*TT*1024;
  for(int idx=blockIdx.x*blockDim.x+threadIdx.x; idx<total; idx+=gridDim.x*blockDim.x){
    int k=idx&1023; int bt=idx>>10; int t=bt%TT; int b=bt/TT;
    unsigned short v;
    if(k<512){ int tok=caps[order[b]*TT+t]; v=f2bf(embW[(size_t)tok*512+k]); }
    else v=gimg[b*512+(k-512)];
    xt[idx]=v;
  }
}

// ---------- GEMM, f32 A row-reordered -> bf16, 256-col tiles ----------
__global__ __launch_bounds__(256) void k_gemm_f32A2(
    const float* __restrict__ A, int lda, int rpb, const int* __restrict__ order,
    const unsigned short* __restrict__ W, const float* __restrict__ bias,
    unsigned short* __restrict__ out, int K)
{
  __shared__ unsigned short As[128][136];
  int tid=threadIdx.x, wave=tid>>6, lane=tid&63, l15=lane&15, l4=lane>>4;
  int mb = blockIdx.y*128;
  f32x4 acc[8][4];
  f32x4 z = {0.f,0.f,0.f,0.f};
  #pragma unroll
  for(int i=0;i<8;i++)
    #pragma unroll
    for(int j=0;j<4;j++) acc[i][j]=z;
  int cch=tid&15, r0=tid>>4;
  int nb = blockIdx.x*256 + wave*64;
  for(int kc=0;kc<K;kc+=128){
    __syncthreads();
    #pragma unroll
    for(int rp=0;rp<8;rp++){
      int r=r0+rp*16;
      int m=mb+r;
      int sb = order[m/rpb]*rpb + m%rpb;
      const float* p = A + (size_t)sb*lda + kc + cch*8;
      float4 v0=*(const float4*)p, v1=*(const float4*)(p+4);
      unsigned short* d=&As[r][cch*8];
      d[0]=f2bf(v0.x); d[1]=f2bf(v0.y); d[2]=f2bf(v0.z); d[3]=f2bf(v0.w);
      d[4]=f2bf(v1.x); d[5]=f2bf(v1.y); d[6]=f2bf(v1.z); d[7]=f2bf(v1.w);
    }
    __syncthreads();
    #pragma unroll
    for(int kk=0;kk<4;kk++){
      bf16x8 bfr[4];
      #pragma unroll
      for(int nt=0;nt<4;nt++)
        bfr[nt] = *(const bf16x8*)(W + (size_t)(nb+nt*16+l15)*K + kc + kk*32 + l4*8);
      #pragma unroll
      for(int mt=0;mt<8;mt++){
        bf16x8 af = *(const bf16x8*)&As[mt*16+l15][kk*32+l4*8];
        #pragma unroll
        for(int nt=0;nt<4;nt++) acc[mt][nt]=mfma16(af,bfr[nt],acc[mt][nt]);
      }
    }
  }
  #pragma unroll
  for(int nt=0;nt<4;nt++){
    int n = nb + nt*16 + l15;
    float bs = bias[n];
    #pragma unroll
    for(int mt=0;mt<8;mt++){
      #pragma unroll
      for(int j=0;j<4;j++){
        int row = mb + mt*16 + l4*4 + j;
        float v = acc[mt][nt][j]+bs; v = v>0.f ? v : 0.f;
        out[(size_t)row*512 + n] = f2bf(v);
      }
    }
  }
}

// ---------- precompute GEMM (cached A) ----------
DEVI void dev_gemm512c(unsigned short (*As)[136], const unsigned short* A, const unsigned short* W,
                       const float* bias, unsigned short* out, int xtile){
  int tid=threadIdx.x, wave=tid>>6, lane=tid&63, l15=lane&15, l4=lane>>4;
  f32x4 acc[8];
  f32x4 z = {0.f,0.f,0.f,0.f};
  #pragma unroll
  for(int i=0;i<8;i++) acc[i]=z;
  int cch=tid&15, r0=tid>>4;
  int nrow = xtile*64 + wave*16 + l15;
  for(int kc=0;kc<512;kc+=128){
    __syncthreads();
    #pragma unroll
    for(int rp=0;rp<8;rp++){
      int r=r0+rp*16;
      *(uint4*)&As[r][cch*8] = *(const uint4*)(A + (size_t)r*512 + kc + cch*8);
    }
    __syncthreads();
    #pragma unroll
    for(int kk=0;kk<4;kk++){
      bf16x8 bfr = *(const bf16x8*)(W + (size_t)nrow*512 + kc + kk*32 + l4*8);
      #pragma unroll
      for(int mt=0;mt<8;mt++){
        bf16x8 af = *(const bf16x8*)&As[mt*16+l15][kk*32+l4*8];
        acc[mt]=mfma16(af,bfr,acc[mt]);
      }
    }
  }
  float bs = bias ? bias[nrow] : 0.f;
  #pragma unroll
  for(int mt=0;mt<8;mt++){
    #pragma unroll
    for(int j=0;j<4;j++){
      int row = mt*16 + l4*4 + j;
      out[(size_t)row*512+nrow]=f2bf(acc[mt][j]+bs);
    }
  }
  __syncthreads();
}

struct PreD { const unsigned short* A; const unsigned short* W; const float* bias; unsigned short* out; };
struct PreD2 { PreD d[2]; };
__global__ __launch_bounds__(256) void k_pre(PreD2 dd){
  __shared__ unsigned short As[128][136];
  PreD g = dd.d[blockIdx.z];
  dev_gemm512c(As, g.A + (size_t)blockIdx.y*128*512, g.W, g.bias,
               g.out + (size_t)blockIdx.y*128*512, blockIdx.x);
}

// ---------- G_x precompute ----------
__global__ __launch_bounds__(256) void k_gx(
    const unsigned short* __restrict__ xt, const unsigned short* __restrict__ w_ih,
    const unsigned short* __restrict__ w_xg,
    const float* __restrict__ bih, const float* __restrict__ bhh,
    const float* __restrict__ bxg, const float* __restrict__ bhg,
    unsigned short* __restrict__ Gx)
{
  __shared__ unsigned short As[128][136];
  int tid=threadIdx.x, wave=tid>>6, lane=tid&63, l15=lane&15, l4=lane>>4;
  int t = blockIdx.y;
  f32x4 acc[8];
  f32x4 z = {0.f,0.f,0.f,0.f};
  #pragma unroll
  for(int i=0;i<8;i++) acc[i]=z;
  int cch=tid&15, r0=tid>>4;
  int n = blockIdx.x*64 + wave*16 + l15;
  const unsigned short* wrow = (n<2048) ? (w_ih + (size_t)n*1024) : (w_xg + (size_t)(n-2048)*1024);
  for(int kc=0;kc<1024;kc+=128){
    __syncthreads();
    #pragma unroll
    for(int rp=0;rp<8;rp++){
      int r=r0+rp*16;
      *(uint4*)&As[r][cch*8] = *(const uint4*)(xt + (size_t)r*(TT*1024) + t*1024 + kc + cch*8);
    }
    __syncthreads();
    #pragma unroll
    for(int kk=0;kk<4;kk++){
      bf16x8 bfr = *(const bf16x8*)(wrow + kc + kk*32 + l4*8);
      #pragma unroll
      for(int mt=0;mt<8;mt++){
        bf16x8 af = *(const bf16x8*)&As[mt*16+l15][kk*32+l4*8];
        acc[mt]=mfma16(af,bfr,acc[mt]);
      }
    }
  }
  float bias = (n<2048) ? (bih[n]+bhh[n]) : (bxg[n-2048]+bhg[n-2048]);
  #pragma unroll
  for(int mt=0;mt<8;mt++){
    int row = mt*16 + l4*4;
    ushort4 o;
    o.x=f2bf(acc[mt][0]+bias); o.y=f2bf(acc[mt][1]+bias);
    o.z=f2bf(acc[mt][2]+bias); o.w=f2bf(acc[mt][3]+bias);
    *(ushort4*)(Gx + ((size_t)t*2560 + n)*128 + row) = o;
  }
}

// ---------- persistent-kernel context ----------
struct PCtx {
  const unsigned short *w_hh, *w_hg, *Gx;
  const unsigned short *w_saff, *w_satt, *w_haff, *w_hatt, *w_ctx, *w_fc;
  const unsigned short *vattn, *SC;
  const float *sab,*stbias,*hab,*htb, *alW,*alb, *cxb, *fcb;
  const int *Bt;
  unsigned short *h_hist;
  unsigned short *stb;
  unsigned short *sbuf;     // TT x 7 x SLOT (Saff,Haff,Satt,Hatt,Scs,Sch,Outl)
  float *dout;
  int *Lf,*SAf,*SBf,*S3f;   // flags at 64B stride
};

// ---------- stage full 128x512 bf16 panel into LDS via one FULLY-UNROLLED bypass burst ----------
DEVI void stage_full(unsigned short (*As2)[520], const unsigned short* src){
  int tid=threadIdx.x;
  #pragma unroll
  for(int i=0;i<32;i++){
    int idx = i*256 + tid;
    int r = idx>>6, c = (idx&63)<<3;
    *(uint4*)&As2[r][c] = byp16(src + (size_t)r*512 + c);
  }
}

// ---------- LSTM step (8 blocks x 64 cols = 4 subtiles), c in regs, masked pair-stores ----------
DEVI void dev_lstmL(unsigned short (*As2)[520], const PCtx& p, int t, int cb,
                    const unsigned short* hprev, unsigned short* hout, float creg[4][2][4]){
  int tid=threadIdx.x, wave=tid>>6, lane=tid&63, l15=lane&15, l4=lane>>4;
  int bt = p.Bt[t];
  __syncthreads();
  if(t>0) stage_full(As2, hprev);
  __syncthreads();
  unsigned short* stt = p.stb + (size_t)t*SLOT;
  for(int g=0;g<4;g++){
    int jb = cb*64 + g*16;
    f32x4 acc[2][5];
    #pragma unroll
    for(int m=0;m<2;m++){
      #pragma unroll
      for(int s=0;s<5;s++){
        int col = (s<4) ? (s*512 + jb + l15) : (2048 + jb + l15);
        int row = (wave*2+m)*16 + l4*4;
        ushort4 gg = *(const ushort4*)(p.Gx + ((size_t)t*2560 + col)*128 + row);
        acc[m][s][0]=bf2f(gg.x); acc[m][s][1]=bf2f(gg.y); acc[m][s][2]=bf2f(gg.z); acc[m][s][3]=bf2f(gg.w);
      }
    }
    if(t>0){
      #pragma unroll
      for(int kk=0;kk<16;kk++){
        int kg = kk*32 + l4*8;
        bf16x8 bfr[5];
        #pragma unroll
        for(int s=0;s<5;s++){
          const unsigned short* wp = (s<4) ? (p.w_hh + (size_t)(s*512+jb+l15)*512 + kg)
                                           : (p.w_hg + (size_t)(jb+l15)*512 + kg);
          bfr[s] = *(const bf16x8*)wp;
        }
        #pragma unroll
        for(int m=0;m<2;m++){
          bf16x8 af = *(const bf16x8*)&As2[(wave*2+m)*16+l15][kk*32+l4*8];
          #pragma unroll
          for(int s=0;s<5;s++) acc[m][s]=mfma16(af,bfr[s],acc[m][s]);
        }
      }
    }
    int j = jb + l15;
    #pragma unroll
    for(int m=0;m<2;m++){
      int mt = wave*2+m;
      #pragma unroll
      for(int jj=0;jj<4;jj++){
        int b = mt*16 + l4*4 + jj;
        float iv = sigm(acc[m][0][jj]);
        float fv = sigm(acc[m][1][jj]);
        float gv = tanhf(acc[m][2][jj]);
        float ov = sigm(acc[m][3][jj]);
        float sv = sigm(acc[m][4][jj]);
        float cn = fv*creg[g][m][jj] + iv*gv;
        float tc = tanhf(cn);
        int hw = f2bf(ov*tc);
        int sw = f2bf(sv*tc);
        int hp = __shfl_xor(hw,1);
        int sp = __shfl_xor(sw,1);
        if(b<bt){
          if((l15&1)==0){
            byps4(hout + (size_t)b*512 + j, (unsigned)(hw&0xffff) | ((unsigned)hp<<16));
            byps4(stt  + (size_t)b*512 + j, (unsigned)(sw&0xffff) | ((unsigned)sp<<16));
          }
          creg[g][m][jj]=cn;
        }
      }
    }
  }
}

// ---------- side GEMM: stage once (full, unrolled), compute ntiles 64-col tiles ----------
DEVI void dev_mmN(unsigned short (*As2)[520], const unsigned short* src, const unsigned short* W,
                  const float* bias, unsigned short* out, int act, int x0, int ntiles, int bt){
  int tid=threadIdx.x, wave=tid>>6, lane=tid&63, l15=lane&15, l4=lane>>4;
  __syncthreads();
  stage_full(As2, src);
  __syncthreads();
  for(int xi=0;xi<ntiles;xi++){
    int nrow = (x0+xi)*64 + wave*16 + l15;
    f32x4 acc[8];
    f32x4 z = {0.f,0.f,0.f,0.f};
    #pragma unroll
    for(int i=0;i<8;i++) acc[i]=z;
    #pragma unroll
    for(int kk=0;kk<16;kk++){
      bf16x8 bfr = *(const bf16x8*)(W + (size_t)nrow*512 + kk*32 + l4*8);
      #pragma unroll
      for(int mt=0;mt<8;mt++){
        bf16x8 af = *(const bf16x8*)&As2[mt*16+l15][kk*32+l4*8];
        acc[mt]=mfma16(af,bfr,acc[mt]);
      }
    }
    float bs = bias ? bias[nrow] : 0.f;
    #pragma unroll
    for(int mt=0;mt<8;mt++){
      #pragma unroll
      for(int j=0;j<4;j++){
        float v = acc[mt][j]+bs;
        if(act==1) v = fmaxf(v,0.f);
        else if(act==2) v = tanhf(v);
        int w = f2bf(v);
        int pw = __shfl_xor(w,1);
        int row = mt*16 + l4*4 + j;
        if((l15&1)==0 && row<bt)
          byps4(out + (size_t)row*512 + (nrow&~1), (unsigned)(w&0xffff) | ((unsigned)pw<<16));
      }
    }
  }
}

// ---------- attention for one batch row ----------
DEVI void dev_attn(float* sS, float* sA, unsigned short* sHA, unsigned short* sSA,
                   int b, const PCtx& p,
                   const unsigned short* satt, const unsigned short* hatt,
                   const unsigned short* scs, const unsigned short* sch,
                   unsigned short* outl){
  int tid=threadIdx.x;
  if(tid<64)       *(uint4*)&sHA[tid*8] = byp16(hatt + (size_t)b*512 + tid*8);
  else if(tid<128){ int q=tid-64; *(uint4*)&sSA[q*8] = byp16(satt + (size_t)b*512 + q*8); }
  __syncthreads();
  int gid=tid>>4, gl=tid&15;
  #pragma unroll
  for(int rp=0;rp<4;rp++){
    int pp = rp*16 + gid;
    float s = 0.f;
    if(pp<50){
      if(pp<NPIX){
        const unsigned short* vp = p.vattn + ((size_t)b*NPIX + pp)*512;
        #pragma unroll 8
        for(int k=gl*32;k<gl*32+32;k++) s += tanhf(bf2f(vp[k]) + bf2f(sHA[k])) * p.alW[k];
      } else {
        #pragma unroll 8
        for(int k=gl*32;k<gl*32+32;k++) s += tanhf(bf2f(sSA[k]) + bf2f(sHA[k])) * p.alW[k];
      }
    }
    #pragma unroll
    for(int off=8;off>=1;off>>=1) s += __shfl_xor(s, off);
    if(gl==0 && pp<50) sS[pp] = s + p.alb[0];
  }
  __syncthreads();
  if(tid<64){
    float sv = (tid<50) ? sS[tid] : -1e30f;
    float m = sv;
    #pragma unroll
    for(int off=32;off>=1;off>>=1) m = fmaxf(m, __shfl_xor(m, off));
    float e = (tid<50) ? expf(sv-m) : 0.f;
    float sum = e;
    #pragma unroll
    for(int off=32;off>=1;off>>=1) sum += __shfl_xor(sum, off);
    if(tid<50) sA[tid] = e/sum;
  }
  __syncthreads();
  float a49 = sA[49];
  {
    int n0 = tid*2;
    unsigned schU = byp4(sch + (size_t)b*512 + n0);
    unsigned scsU = byp4(scs + (size_t)b*512 + n0);
    float c0 = bf2f((unsigned short)schU), c1 = bf2f((unsigned short)(schU>>16));
    float s0 = bf2f((unsigned short)scsU), s1 = bf2f((unsigned short)(scsU>>16));
    float acc0 = c0 + a49*s0 + p.cxb[n0];
    float acc1 = c1 + a49*s1 + p.cxb[n0+1];
    const unsigned short* sp = p.SC + (size_t)b*NPIX*512 + n0;
    #pragma unroll 7
    for(int pp=0;pp<NPIX;pp++){
      unsigned u = *(const unsigned*)(sp + (size_t)pp*512);
      acc0 += sA[pp]*bf2f((unsigned short)u);
      acc1 += sA[pp]*bf2f((unsigned short)(u>>16));
    }
    unsigned o = ((unsigned)f2bf(tanhf(acc1))<<16) | (unsigned)(f2bf(tanhf(acc0))&0xffff);
    byps4(outl + (size_t)b*512 + n0, o);
  }
  __syncthreads();
}

// ---------- fc: stage outl once (full, unrolled), ~10 tiles per block ----------
DEVI void dev_fcF(unsigned short (*As2)[520], const PCtx& p, int t, int f,
                  const unsigned short* outl){
  int tid=threadIdx.x;
  int bt = p.Bt[t];
  __syncthreads();
  stage_full(As2, outl);
  __syncthreads();
  int wave=tid>>6, lane=tid&63, l15=lane&15, l4=lane>>4;
  for(int x=f; x<157; x+=16){
    f32x4 acc[8];
    f32x4 z = {0.f,0.f,0.f,0.f};
    #pragma unroll
    for(int i=0;i<8;i++) acc[i]=z;
    int nbase = x*64 + wave*16;
    int nr = nbase + l15; if(nr > VOCAB-1) nr = VOCAB-1;
    #pragma unroll 4
    for(int kk=0;kk<16;kk++){
      bf16x8 bfr = *(const bf16x8*)(p.w_fc + (size_t)nr*512 + kk*32 + l4*8);
      #pragma unroll
      for(int mt=0;mt<8;mt++){
        if(mt*16 < bt){
          bf16x8 af = *(const bf16x8*)&As2[mt*16+l15][kk*32+l4*8];
          acc[mt]=mfma16(af,bfr,acc[mt]);
        }
      }
    }
    int n = nbase + l15; bool nok = n < VOCAB;
    float bs = nok ? p.fcb[n] : 0.f;
    #pragma unroll
    for(int mt=0;mt<8;mt++){
      #pragma unroll
      for(int j=0;j<4;j++){
        int b = mt*16 + l4*4 + j;
        float v = (b<bt) ? (acc[mt][j]+bs) : 0.f;
        if(nok) p.dout[(size_t)b*(TT*VOCAB) + (size_t)t*VOCAB + n] = v;
      }
    }
  }
}

// ---------- persistent kernel: L(0-7) SA(8-11) SB(12-19) AT(20-83) FC(84-99) ----------
__global__ __launch_bounds__(256) void k_persist(PCtx p){
  __shared__ __align__(16) char smem[133760];
  auto As2 = (unsigned short (*)[520])smem;
  unsigned short* sHA = (unsigned short*)smem;
  unsigned short* sSA = sHA + 512;
  float* sS = (float*)(smem + 2048);
  float* sA = sS + 64;
  int cb = blockIdx.x;

  if(cb < 8){
    float creg[4][2][4];
    #pragma unroll
    for(int g=0;g<4;g++)
      #pragma unroll
      for(int m=0;m<2;m++)
        #pragma unroll
        for(int j=0;j<4;j++) creg[g][m][j]=0.f;
    for(int t=0;t<TT;t++){
      if(t>0) waitarr(p.Lf, 8, t);
      dev_lstmL(As2, p, t, cb, p.h_hist + (size_t)t*SLOT, p.h_hist + (size_t)(t+1)*SLOT, creg);
      setflag(p.Lf + cb*16, t+1);
    }
  } else if(cb < 12){
    int w = cb-8;
    for(int t=0;t<TT;t++){
      waitarr(p.Lf, 8, t+1);
      int bt = p.Bt[t];
      unsigned short* S = p.sbuf + (size_t)t*7*SLOT;
      if(w<2) dev_mmN(As2, p.stb + (size_t)t*SLOT,        p.w_saff, p.sab, S,      1, w*4,     4, bt);
      else    dev_mmN(As2, p.h_hist + (size_t)(t+1)*SLOT, p.w_haff, p.hab, S+SLOT, 2, (w-2)*4, 4, bt);
      setflag(p.SAf + w*16, t+1);
    }
  } else if(cb < 20){
    int w = cb-12;
    int q = w>>1, x0 = (w&1)*4;
    for(int t=0;t<TT;t++){
      waitarr(p.SAf, 4, t+1);
      int bt = p.Bt[t];
      unsigned short* S = p.sbuf + (size_t)t*7*SLOT;
      const unsigned short* src = (q==0||q==2) ? S : S+SLOT;
      const unsigned short* W   = (q==0)? p.w_satt : (q==1)? p.w_hatt : p.w_ctx;
      const float* bias         = (q==0)? p.stbias : (q==1)? p.htb    : nullptr;
      unsigned short* out       = S + (size_t)(2+q)*SLOT;
      dev_mmN(As2, src, W, bias, out, 0, x0, 4, bt);
      setflag(p.SBf + w*16, t+1);
    }
  } else if(cb < 84){
    int w = cb-20;
    for(int t=0;t<TT;t++){
      waitarr(p.SBf, 8, t+1);
      int bt = p.Bt[t];
      unsigned short* S = p.sbuf + (size_t)t*7*SLOT;
      #pragma unroll
      for(int r=0;r<2;r++){
        int b = w*2+r;
        if(b < bt) dev_attn(sS,sA,sHA,sSA, b, p, S+2*SLOT, S+3*SLOT, S+4*SLOT, S+5*SLOT, S+6*SLOT);
      }
      setflag(p.S3f + w*16, t+1);
    }
  } else {
    int f = cb-84;
    for(int t=0;t<TT;t++){
      waitarr(p.S3f, 64, t+1);
      unsigned short* S = p.sbuf + (size_t)t*7*SLOT;
      dev_fcF(As2, p, t, f, S+6*SLOT);
    }
  }
}

// ---------- host launch ----------
extern "C" void kernel_launch(void* const* d_in, const int* in_sizes, int n_in,
                              void* d_out, int out_size, void* d_ws, size_t ws_size,
                              hipStream_t stream)
{
  const float* enc  =(const float*)d_in[0];
  const float* gfeat=(const float*)d_in[1];
  const int*   caps =(const int*)d_in[2];
  const int*   lens =(const int*)d_in[3];
  const float* embW =(const float*)d_in[4];
  const float* e2hW =(const float*)d_in[5];  const float* e2hb=(const float*)d_in[6];
  const float* gfW  =(const float*)d_in[7];  const float* gfb =(const float*)d_in[8];
  const float* fcW  =(const float*)d_in[9];  const float* fcb =(const float*)d_in[10];
  const float* WihF =(const float*)d_in[11]; const float* bih =(const float*)d_in[12];
  const float* WhhF =(const float*)d_in[13]; const float* bhh =(const float*)d_in[14];
  const float* xgWF =(const float*)d_in[15]; const float* bxg =(const float*)d_in[16];
  const float* hgWF =(const float*)d_in[17]; const float* bhg =(const float*)d_in[18];
  const float* saWF =(const float*)d_in[19]; const float* sab =(const float*)d_in[20];
  const float* stWF =(const float*)d_in[21]; const float* stbias=(const float*)d_in[22];
  const float* haWF =(const float*)d_in[23]; const float* hab =(const float*)d_in[24];
  const float* htWF =(const float*)d_in[25]; const float* htb =(const float*)d_in[26];
  const float* vaWF =(const float*)d_in[27]; const float* vab =(const float*)d_in[28];
  const float* alW  =(const float*)d_in[29]; const float* alb =(const float*)d_in[30];
  const float* cxWF =(const float*)d_in[31]; const float* cxb =(const float*)d_in[32];

  char* base=(char*)d_ws; size_t off=0;
  auto alloc=[&](size_t bytes)->void*{ void* r=base+off; off += (bytes+255)&~(size_t)255; return r; };

  int* order=(int*)alloc(BB*4);
  int* Bt   =(int*)alloc(32*4);
  unsigned short* w_e2h =(unsigned short*)alloc((size_t)512*2048*2);   // aliased by stb_hist
  unsigned short* w_gf  =(unsigned short*)alloc((size_t)512*2048*2);   // (contiguous)
  unsigned short* w_fc  =(unsigned short*)alloc((size_t)VOCAB*512*2);
  unsigned short* w_ih  =(unsigned short*)alloc((size_t)2048*1024*2);
  unsigned short* w_hh  =(unsigned short*)alloc((size_t)2048*512*2);
  unsigned short* w_xg  =(unsigned short*)alloc((size_t)512*1024*2);
  unsigned short* w_hg  =(unsigned short*)alloc((size_t)512*512*2);
  unsigned short* w_saff=(unsigned short*)alloc((size_t)512*512*2);
  unsigned short* w_satt=(unsigned short*)alloc((size_t)512*512*2);
  unsigned short* w_haff=(unsigned short*)alloc((size_t)512*512*2);
  unsigned short* w_hatt=(unsigned short*)alloc((size_t)512*512*2);
  unsigned short* w_vatt=(unsigned short*)alloc((size_t)512*512*2);
  unsigned short* w_ctx =(unsigned short*)alloc((size_t)512*512*2);
  unsigned short* spatial=(unsigned short*)alloc((size_t)BB*NPIX*512*2); // aliased by h_hist
  unsigned short* vattn  =(unsigned short*)alloc((size_t)BB*NPIX*512*2);
  unsigned short* SC     =(unsigned short*)alloc((size_t)BB*NPIX*512*2);
  unsigned short* gimg   =(unsigned short*)alloc((size_t)BB*512*2);
  unsigned short* xt     =(unsigned short*)alloc((size_t)BB*TT*1024*2);
  int* flags =(int*)alloc(16384);
  unsigned short* Gx  =(unsigned short*)alloc((size_t)TT*2560*128*2);
  unsigned short* sbuf=(unsigned short*)alloc((size_t)TT*7*SLOT*2);

  unsigned short* stb_hist = w_e2h;              // 30 slots = 3.93MB <= 8MB (w_e2h+w_gf)
  unsigned short* h_hist   = spatial;            // 31 slots = 4.06MB <= 6.42MB

  k_sort<<<1,BB,0,stream>>>(lens, order, Bt);

  WC13 wc;
  const float* srcs[13] = {e2hW,gfW,fcW,WihF,WhhF,xgWF,hgWF,saWF,stWF,haWF,htWF,vaWF,cxWF};
  unsigned short* dsts[13] = {w_e2h,w_gf,w_fc,w_ih,w_hh,w_xg,w_hg,w_saff,w_satt,w_haff,w_hatt,w_vatt,w_ctx};
  int ns[13] = {512*2048,512*2048,VOCAB*512,2048*1024,2048*512,512*1024,512*512,512*512,512*512,512*512,512*512,512*512,512*512};
  for(int i=0;i<13;i++){ wc.src[i]=srcs[i]; wc.dst[i]=dsts[i]; wc.n[i]=ns[i]; }
  k_wconv<<<1024,256,0,stream>>>(wc);

  k_gemm_f32A2<<<dim3(2,NPIX),256,0,stream>>>(enc, ENCD, NPIX, order, w_e2h, e2hb, spatial, ENCD);
  k_gemm_f32A2<<<dim3(2,1),  256,0,stream>>>(gfeat, ENCD, 1, order, w_gf, gfb, gimg, ENCD);
  k_xt<<<1024,256,0,stream>>>(caps, order, embW, gimg, xt);
  {
    PreD2 dv{};
    dv.d[0] = PreD{spatial, w_vatt, vab,     vattn};
    dv.d[1] = PreD{spatial, w_ctx,  nullptr, SC};
    k_pre<<<dim3(8,NPIX,2),256,0,stream>>>(dv);
  }
  k_gx<<<dim3(40,TT),256,0,stream>>>(xt, w_ih, w_xg, bih, bhh, bxg, bhg, Gx);

  hipMemsetAsync(h_hist, 0, (size_t)SLOT*2, stream);
  hipMemsetAsync(flags, 0, 16384, stream);

  PCtx pc;
  pc.w_hh=w_hh; pc.w_hg=w_hg; pc.Gx=Gx;
  pc.w_saff=w_saff; pc.w_satt=w_satt; pc.w_haff=w_haff; pc.w_hatt=w_hatt; pc.w_ctx=w_ctx; pc.w_fc=w_fc;
  pc.vattn=vattn; pc.SC=SC;
  pc.sab=sab; pc.stbias=stbias; pc.hab=hab; pc.htb=htb;
  pc.alW=alW; pc.alb=alb; pc.cxb=cxb; pc.fcb=fcb;
  pc.Bt=Bt;
  pc.h_hist=h_hist; pc.stb=stb_hist; pc.sbuf=sbuf;
  pc.dout=(float*)d_out;
  pc.Lf  = flags;            // 8 flags @ 64B stride
  pc.SAf = flags + 128;      // 4 flags
  pc.SBf = flags + 192;      // 8 flags
  pc.S3f = flags + 320;      // 64 flags

  k_persist<<<100,256,0,stream>>>(pc);
}

// Round 11
// 2803.326 us; speedup vs baseline: 3.1553x; 3.1553x over previous
//
#include <hip/hip_runtime.h>
#include <hip/hip_bf16.h>
#include <cstdint>
#include <cstddef>

#define DEVI __device__ __forceinline__

// ---------- constants ----------
#define BB 128
#define TT 30
#define VOCAB 10000
#define ENCD 2048
#define NPIX 49
#define SLOT 65536   // 128*512 elements

typedef __attribute__((ext_vector_type(8))) short bf16x8;
typedef __attribute__((ext_vector_type(4))) float f32x4;

DEVI float bf2f(unsigned short u){ union{float f; unsigned int i;} x; x.i=((unsigned)u)<<16; return x.f; }
DEVI unsigned short f2bf(float f){ union{float f; unsigned int i;} x; x.f=f; unsigned r=x.i + 0x7fffu + ((x.i>>16)&1u); return (unsigned short)(r>>16); }
DEVI float sigm(float x){ return 1.0f/(1.0f+expf(-x)); }
DEVI f32x4 mfma16(bf16x8 a, bf16x8 b, f32x4 c){ return __builtin_amdgcn_mfma_f32_16x16x32_bf16(a,b,c,0,0,0); }

// ---------- sync: relaxed poll (no acquire), RELEASE flag store (wbl2 pushes data to CP) ----------
// Protocol correctness: every cross-block tensor address is written once per launch and is
// never cached on a consumer XCD before its flag is observed -> consumer load misses -> CP.
DEVI void waitarr(int* base, int n, int thresh){
  __syncthreads();
  if(threadIdx.x < 64){
    for(;;){
      int v = (threadIdx.x<n) ? __hip_atomic_load(base + threadIdx.x*16, __ATOMIC_RELAXED, __HIP_MEMORY_SCOPE_AGENT)
                              : 0x7fffffff;
      if(__all(v >= thresh)) break;
      __builtin_amdgcn_s_sleep(8);
    }
  }
  asm volatile("" ::: "memory");
  __syncthreads();
}
DEVI void setflag(int* f, int val){
  __syncthreads();   // all waves' normal stores drained to L2
  if(threadIdx.x==0) __hip_atomic_store(f, val, __ATOMIC_RELEASE, __HIP_MEMORY_SCOPE_AGENT); // wbl2 + store
}

// ---------- sort: stable descending by length ----------
__global__ void k_sort(const int* __restrict__ lens, int* __restrict__ order, int* __restrict__ Bt){
  __shared__ int L[BB];
  int i = threadIdx.x;
  L[i] = lens[i];
  __syncthreads();
  int li = L[i]; int rank = 0;
  for(int j=0;j<BB;j++){ int lj=L[j]; rank += (lj>li) || (lj==li && j<i); }
  order[rank] = i;
  if(i<TT){ int c=0; for(int j=0;j<BB;j++) c += (L[j]>i); Bt[i]=c; }
}

// ---------- weight f32 -> bf16 conversion ----------
struct WC13 { const float* src[13]; unsigned short* dst[13]; int n[13]; };
__global__ void k_wconv(WC13 wc){
  int stride = gridDim.x*blockDim.x;
  int tid0 = blockIdx.x*blockDim.x + threadIdx.x;
  for(int s=0;s<13;s++){
    const float4* src=(const float4*)wc.src[s];
    int n4 = wc.n[s]>>2;
    ushort4* dst=(ushort4*)wc.dst[s];
    for(int i=tid0;i<n4;i+=stride){
      float4 v=src[i];
      ushort4 o; o.x=f2bf(v.x); o.y=f2bf(v.y); o.z=f2bf(v.z); o.w=f2bf(v.w);
      dst[i]=o;
    }
  }
}

// ---------- xt build ----------
__global__ void k_xt(const int* __restrict__ caps, const int* __restrict__ order,
                     const float* __restrict__ embW, const unsigned short* __restrict__ gimg,
                     unsigned short* __restrict__ xt){
  int total=BB*TT*1024;
  for(int idx=blockIdx.x*blockDim.x+threadIdx.x; idx<total; idx+=gridDim.x*blockDim.x){
    int k=idx&1023; int bt=idx>>10; int t=bt%TT; int b=bt/TT;
    unsigned short v;
    if(k<512){ int tok=caps[order[b]*TT+t]; v=f2bf(embW[(size_t)tok*512+k]); }
    else v=gimg[b*512+(k-512)];
    xt[idx]=v;
  }
}

// ---------- GEMM, f32 A row-reordered -> bf16, 256-col tiles ----------
__global__ __launch_bounds__(256) void k_gemm_f32A2(
    const float* __restrict__ A, int lda, int rpb, const int* __restrict__ order,
    const unsigned short* __restrict__ W, const float* __restrict__ bias,
    unsigned short* __restrict__ out, int K)
{
  __shared__ unsigned short As[128][136];
  int tid=threadIdx.x, wave=tid>>6, lane=tid&63, l15=lane&15, l4=lane>>4;
  int mb = blockIdx.y*128;
  f32x4 acc[8][4];
  f32x4 z = {0.f,0.f,0.f,0.f};
  #pragma unroll
  for(int i=0;i<8;i++)
    #pragma unroll
    for(int j=0;j<4;j++) acc[i][j]=z;
  int cch=tid&15, r0=tid>>4;
  int nb = blockIdx.x*256 + wave*64;
  for(int kc=0;kc<K;kc+=128){
    __syncthreads();
    #pragma unroll
    for(int rp=0;rp<8;rp++){
      int r=r0+rp*16;
      int m=mb+r;
      int sb = order[m/rpb]*rpb + m%rpb;
      const float* p = A + (size_t)sb*lda + kc + cch*8;
      float4 v0=*(const float4*)p, v1=*(const float4*)(p+4);
      unsigned short* d=&As[r][cch*8];
      d[0]=f2bf(v0.x); d[1]=f2bf(v0.y); d[2]=f2bf(v0.z); d[3]=f2bf(v0.w);
      d[4]=f2bf(v1.x); d[5]=f2bf(v1.y); d[6]=f2bf(v1.z); d[7]=f2bf(v1.w);
    }
    __syncthreads();
    #pragma unroll
    for(int kk=0;kk<4;kk++){
      bf16x8 bfr[4];
      #pragma unroll
      for(int nt=0;nt<4;nt++)
        bfr[nt] = *(const bf16x8*)(W + (size_t)(nb+nt*16+l15)*K + kc + kk*32 + l4*8);
      #pragma unroll
      for(int mt=0;mt<8;mt++){
        bf16x8 af = *(const bf16x8*)&As[mt*16+l15][kk*32+l4*8];
        #pragma unroll
        for(int nt=0;nt<4;nt++) acc[mt][nt]=mfma16(af,bfr[nt],acc[mt][nt]);
      }
    }
  }
  #pragma unroll
  for(int nt=0;nt<4;nt++){
    int n = nb + nt*16 + l15;
    float bs = bias[n];
    #pragma unroll
    for(int mt=0;mt<8;mt++){
      #pragma unroll
      for(int j=0;j<4;j++){
        int row = mb + mt*16 + l4*4 + j;
        float v = acc[mt][nt][j]+bs; v = v>0.f ? v : 0.f;
        out[(size_t)row*512 + n] = f2bf(v);
      }
    }
  }
}

// ---------- precompute GEMM (cached A) ----------
DEVI void dev_gemm512c(unsigned short (*As)[136], const unsigned short* A, const unsigned short* W,
                       const float* bias, unsigned short* out, int xtile){
  int tid=threadIdx.x, wave=tid>>6, lane=tid&63, l15=lane&15, l4=lane>>4;
  f32x4 acc[8];
  f32x4 z = {0.f,0.f,0.f,0.f};
  #pragma unroll
  for(int i=0;i<8;i++) acc[i]=z;
  int cch=tid&15, r0=tid>>4;
  int nrow = xtile*64 + wave*16 + l15;
  for(int kc=0;kc<512;kc+=128){
    __syncthreads();
    #pragma unroll
    for(int rp=0;rp<8;rp++){
      int r=r0+rp*16;
      *(uint4*)&As[r][cch*8] = *(const uint4*)(A + (size_t)r*512 + kc + cch*8);
    }
    __syncthreads();
    #pragma unroll
    for(int kk=0;kk<4;kk++){
      bf16x8 bfr = *(const bf16x8*)(W + (size_t)nrow*512 + kc + kk*32 + l4*8);
      #pragma unroll
      for(int mt=0;mt<8;mt++){
        bf16x8 af = *(const bf16x8*)&As[mt*16+l15][kk*32+l4*8];
        acc[mt]=mfma16(af,bfr,acc[mt]);
      }
    }
  }
  float bs = bias ? bias[nrow] : 0.f;
  #pragma unroll
  for(int mt=0;mt<8;mt++){
    #pragma unroll
    for(int j=0;j<4;j++){
      int row = mt*16 + l4*4 + j;
      out[(size_t)row*512+nrow]=f2bf(acc[mt][j]+bs);
    }
  }
  __syncthreads();
}

struct PreD { const unsigned short* A; const unsigned short* W; const float* bias; unsigned short* out; };
struct PreD2 { PreD d[2]; };
__global__ __launch_bounds__(256) void k_pre(PreD2 dd){
  __shared__ unsigned short As[128][136];
  PreD g = dd.d[blockIdx.z];
  dev_gemm512c(As, g.A + (size_t)blockIdx.y*128*512, g.W, g.bias,
               g.out + (size_t)blockIdx.y*128*512, blockIdx.x);
}

// ---------- G_x precompute ----------
__global__ __launch_bounds__(256) void k_gx(
    const unsigned short* __restrict__ xt, const unsigned short* __restrict__ w_ih,
    const unsigned short* __restrict__ w_xg,
    const float* __restrict__ bih, const float* __restrict__ bhh,
    const float* __restrict__ bxg, const float* __restrict__ bhg,
    unsigned short* __restrict__ Gx)
{
  __shared__ unsigned short As[128][136];
  int tid=threadIdx.x, wave=tid>>6, lane=tid&63, l15=lane&15, l4=lane>>4;
  int t = blockIdx.y;
  f32x4 acc[8];
  f32x4 z = {0.f,0.f,0.f,0.f};
  #pragma unroll
  for(int i=0;i<8;i++) acc[i]=z;
  int cch=tid&15, r0=tid>>4;
  int n = blockIdx.x*64 + wave*16 + l15;
  const unsigned short* wrow = (n<2048) ? (w_ih + (size_t)n*1024) : (w_xg + (size_t)(n-2048)*1024);
  for(int kc=0;kc<1024;kc+=128){
    __syncthreads();
    #pragma unroll
    for(int rp=0;rp<8;rp++){
      int r=r0+rp*16;
      *(uint4*)&As[r][cch*8] = *(const uint4*)(xt + (size_t)r*(TT*1024) + t*1024 + kc + cch*8);
    }
    __syncthreads();
    #pragma unroll
    for(int kk=0;kk<4;kk++){
      bf16x8 bfr = *(const bf16x8*)(wrow + kc + kk*32 + l4*8);
      #pragma unroll
      for(int mt=0;mt<8;mt++){
        bf16x8 af = *(const bf16x8*)&As[mt*16+l15][kk*32+l4*8];
        acc[mt]=mfma16(af,bfr,acc[mt]);
      }
    }
  }
  float bias = (n<2048) ? (bih[n]+bhh[n]) : (bxg[n-2048]+bhg[n-2048]);
  #pragma unroll
  for(int mt=0;mt<8;mt++){
    int row = mt*16 + l4*4;
    ushort4 o;
    o.x=f2bf(acc[mt][0]+bias); o.y=f2bf(acc[mt][1]+bias);
    o.z=f2bf(acc[mt][2]+bias); o.w=f2bf(acc[mt][3]+bias);
    *(ushort4*)(Gx + ((size_t)t*2560 + n)*128 + row) = o;
  }
}

// ---------- persistent-kernel context ----------
struct PCtx {
  const unsigned short *w_hh, *w_hg, *Gx;
  const unsigned short *w_saff, *w_satt, *w_haff, *w_hatt, *w_ctx, *w_fc;
  const unsigned short *vattn, *SC;
  const float *sab,*stbias,*hab,*htb, *alW,*alb, *cxb, *fcb;
  const int *Bt;
  unsigned short *h_hist;   // (TT+1) slots; slot t+1 written by step t
  unsigned short *stb;      // TT slots
  unsigned short *sbuf;     // TT x 7 x SLOT (Saff,Haff,Satt,Hatt,Scs,Sch,Outl)
  float *dout;
  int *Lf,*SAf,*SBf,*S3f;   // flags at 64B stride
};

// ---------- stage full 128x512 bf16 panel into LDS via NORMAL coalesced loads ----------
DEVI void stage_full(unsigned short (*As2)[520], const unsigned short* src){
  int tid=threadIdx.x;
  #pragma unroll
  for(int i=0;i<32;i++){
    int idx = i*256 + tid;
    int r = idx>>6, c = (idx&63)<<3;
    *(uint4*)&As2[r][c] = *(const uint4*)(src + (size_t)r*512 + c);
  }
}

// ---------- LSTM step (32 blocks x 16 cols), c in regs, masked normal pair-stores ----------
DEVI void dev_lstmP(unsigned short (*As2)[520], const PCtx& p, int t, int cb,
                    const unsigned short* hprev, unsigned short* hout, float creg[2][4]){
  int tid=threadIdx.x, wave=tid>>6, lane=tid&63, l15=lane&15, l4=lane>>4;
  int jb = cb*16;
  int bt = p.Bt[t];
  __syncthreads();
  if(t>0) stage_full(As2, hprev);
  f32x4 acc[2][5];
  #pragma unroll
  for(int m=0;m<2;m++){
    #pragma unroll
    for(int s=0;s<5;s++){
      int col = (s<4) ? (s*512 + jb + l15) : (2048 + jb + l15);
      int row = (wave*2+m)*16 + l4*4;
      ushort4 g = *(const ushort4*)(p.Gx + ((size_t)t*2560 + col)*128 + row);
      acc[m][s][0]=bf2f(g.x); acc[m][s][1]=bf2f(g.y); acc[m][s][2]=bf2f(g.z); acc[m][s][3]=bf2f(g.w);
    }
  }
  __syncthreads();
  if(t>0){
    #pragma unroll
    for(int kk=0;kk<16;kk++){
      int kg = kk*32 + l4*8;
      bf16x8 bfr[5];
      #pragma unroll
      for(int s=0;s<5;s++){
        const unsigned short* wp = (s<4) ? (p.w_hh + (size_t)(s*512+jb+l15)*512 + kg)
                                         : (p.w_hg + (size_t)(jb+l15)*512 + kg);
        bfr[s] = *(const bf16x8*)wp;
      }
      #pragma unroll
      for(int m=0;m<2;m++){
        bf16x8 af = *(const bf16x8*)&As2[(wave*2+m)*16+l15][kk*32+l4*8];
        #pragma unroll
        for(int s=0;s<5;s++) acc[m][s]=mfma16(af,bfr[s],acc[m][s]);
      }
    }
  }
  int j = jb + l15;
  unsigned short* stt = p.stb + (size_t)t*SLOT;
  #pragma unroll
  for(int m=0;m<2;m++){
    int mt = wave*2+m;
    #pragma unroll
    for(int jj=0;jj<4;jj++){
      int b = mt*16 + l4*4 + jj;
      float iv = sigm(acc[m][0][jj]);
      float fv = sigm(acc[m][1][jj]);
      float gv = tanhf(acc[m][2][jj]);
      float ov = sigm(acc[m][3][jj]);
      float sv = sigm(acc[m][4][jj]);
      float cn = fv*creg[m][jj] + iv*gv;
      float tc = tanhf(cn);
      int hw = f2bf(ov*tc);
      int sw = f2bf(sv*tc);
      int hp = __shfl_xor(hw,1);
      int sp = __shfl_xor(sw,1);
      if(b<bt){
        if((l15&1)==0){
          *(unsigned*)(hout + (size_t)b*512 + j) = (unsigned)(hw&0xffff) | ((unsigned)hp<<16);
          *(unsigned*)(stt  + (size_t)b*512 + j) = (unsigned)(sw&0xffff) | ((unsigned)sp<<16);
        }
        creg[m][jj]=cn;
      }
    }
  }
}

// ---------- side GEMM: stage once (normal loads), one 64-col tile, masked stores ----------
DEVI void dev_mm1(unsigned short (*As2)[520], const unsigned short* src, const unsigned short* W,
                  const float* bias, unsigned short* out, int act, int xtile, int bt){
  int tid=threadIdx.x, wave=tid>>6, lane=tid&63, l15=lane&15, l4=lane>>4;
  __syncthreads();
  stage_full(As2, src);
  __syncthreads();
  int nrow = xtile*64 + wave*16 + l15;
  f32x4 acc[8];
  f32x4 z = {0.f,0.f,0.f,0.f};
  #pragma unroll
  for(int i=0;i<8;i++) acc[i]=z;
  #pragma unroll
  for(int kk=0;kk<16;kk++){
    bf16x8 bfr = *(const bf16x8*)(W + (size_t)nrow*512 + kk*32 + l4*8);
    #pragma unroll
    for(int mt=0;mt<8;mt++){
      bf16x8 af = *(const bf16x8*)&As2[mt*16+l15][kk*32+l4*8];
      acc[mt]=mfma16(af,bfr,acc[mt]);
    }
  }
  float bs = bias ? bias[nrow] : 0.f;
  #pragma unroll
  for(int mt=0;mt<8;mt++){
    #pragma unroll
    for(int j=0;j<4;j++){
      float v = acc[mt][j]+bs;
      if(act==1) v = fmaxf(v,0.f);
      else if(act==2) v = tanhf(v);
      int w = f2bf(v);
      int pw = __shfl_xor(w,1);
      int row = mt*16 + l4*4 + j;
      if((l15&1)==0 && row<bt)
        *(unsigned*)(out + (size_t)row*512 + (nrow&~1)) = (unsigned)(w&0xffff) | ((unsigned)pw<<16);
    }
  }
}

// ---------- attention for one batch row (normal loads) ----------
DEVI void dev_attn(float* sS, float* sA, unsigned short* sHA, unsigned short* sSA,
                   int b, const PCtx& p,
                   const unsigned short* satt, const unsigned short* hatt,
                   const unsigned short* scs, const unsigned short* sch,
                   unsigned short* outl){
  int tid=threadIdx.x;
  if(tid<64)       *(uint4*)&sHA[tid*8] = *(const uint4*)(hatt + (size_t)b*512 + tid*8);
  else if(tid<128){ int q=tid-64; *(uint4*)&sSA[q*8] = *(const uint4*)(satt + (size_t)b*512 + q*8); }
  __syncthreads();
  int gid=tid>>4, gl=tid&15;
  #pragma unroll
  for(int rp=0;rp<4;rp++){
    int pp = rp*16 + gid;
    float s = 0.f;
    if(pp<50){
      if(pp<NPIX){
        const unsigned short* vp = p.vattn + ((size_t)b*NPIX + pp)*512;
        #pragma unroll 8
        for(int k=gl*32;k<gl*32+32;k++) s += tanhf(bf2f(vp[k]) + bf2f(sHA[k])) * p.alW[k];
      } else {
        #pragma unroll 8
        for(int k=gl*32;k<gl*32+32;k++) s += tanhf(bf2f(sSA[k]) + bf2f(sHA[k])) * p.alW[k];
      }
    }
    #pragma unroll
    for(int off=8;off>=1;off>>=1) s += __shfl_xor(s, off);
    if(gl==0 && pp<50) sS[pp] = s + p.alb[0];
  }
  __syncthreads();
  if(tid<64){
    float sv = (tid<50) ? sS[tid] : -1e30f;
    float m = sv;
    #pragma unroll
    for(int off=32;off>=1;off>>=1) m = fmaxf(m, __shfl_xor(m, off));
    float e = (tid<50) ? expf(sv-m) : 0.f;
    float sum = e;
    #pragma unroll
    for(int off=32;off>=1;off>>=1) sum += __shfl_xor(sum, off);
    if(tid<50) sA[tid] = e/sum;
  }
  __syncthreads();
  float a49 = sA[49];
  {
    int n0 = tid*2;
    unsigned schU = *(const unsigned*)(sch + (size_t)b*512 + n0);
    unsigned scsU = *(const unsigned*)(scs + (size_t)b*512 + n0);
    float c0 = bf2f((unsigned short)schU), c1 = bf2f((unsigned short)(schU>>16));
    float s0 = bf2f((unsigned short)scsU), s1 = bf2f((unsigned short)(scsU>>16));
    float acc0 = c0 + a49*s0 + p.cxb[n0];
    float acc1 = c1 + a49*s1 + p.cxb[n0+1];
    const unsigned short* sp = p.SC + (size_t)b*NPIX*512 + n0;
    #pragma unroll 7
    for(int pp=0;pp<NPIX;pp++){
      unsigned u = *(const unsigned*)(sp + (size_t)pp*512);
      acc0 += sA[pp]*bf2f((unsigned short)u);
      acc1 += sA[pp]*bf2f((unsigned short)(u>>16));
    }
    unsigned o = ((unsigned)f2bf(tanhf(acc1))<<16) | (unsigned)(f2bf(tanhf(acc0))&0xffff);
    *(unsigned*)(outl + (size_t)b*512 + n0) = o;
  }
  __syncthreads();
}

// ---------- fc: stage outl once (normal loads), 1-2 tiles per block ----------
DEVI void dev_fcF(unsigned short (*As2)[520], const PCtx& p, int t, int f,
                  const unsigned short* outl){
  int tid=threadIdx.x;
  int bt = p.Bt[t];
  __syncthreads();
  stage_full(As2, outl);
  __syncthreads();
  int wave=tid>>6, lane=tid&63, l15=lane&15, l4=lane>>4;
  for(int x=f; x<157; x+=112){
    f32x4 acc[8];
    f32x4 z = {0.f,0.f,0.f,0.f};
    #pragma unroll
    for(int i=0;i<8;i++) acc[i]=z;
    int nbase = x*64 + wave*16;
    int nr = nbase + l15; if(nr > VOCAB-1) nr = VOCAB-1;
    #pragma unroll 4
    for(int kk=0;kk<16;kk++){
      bf16x8 bfr = *(const bf16x8*)(p.w_fc + (size_t)nr*512 + kk*32 + l4*8);
      #pragma unroll
      for(int mt=0;mt<8;mt++){
        if(mt*16 < bt){
          bf16x8 af = *(const bf16x8*)&As2[mt*16+l15][kk*32+l4*8];
          acc[mt]=mfma16(af,bfr,acc[mt]);
        }
      }
    }
    int n = nbase + l15; bool nok = n < VOCAB;
    float bs = nok ? p.fcb[n] : 0.f;
    #pragma unroll
    for(int mt=0;mt<8;mt++){
      #pragma unroll
      for(int j=0;j<4;j++){
        int b = mt*16 + l4*4 + j;
        float v = (b<bt) ? (acc[mt][j]+bs) : 0.f;
        if(nok) p.dout[(size_t)b*(TT*VOCAB) + (size_t)t*VOCAB + n] = v;
      }
    }
  }
}

// ---------- persistent kernel: L(0-31) SA(32-47) SB(48-79) AT(80-143) FC(144-255) ----------
__global__ __launch_bounds__(256) void k_persist(PCtx p){
  __shared__ __align__(16) char smem[133760];
  auto As2 = (unsigned short (*)[520])smem;
  unsigned short* sHA = (unsigned short*)smem;
  unsigned short* sSA = sHA + 512;
  float* sS = (float*)(smem + 2048);
  float* sA = sS + 64;
  int cb = blockIdx.x;

  if(cb < 32){
    float creg[2][4];
    #pragma unroll
    for(int m=0;m<2;m++)
      #pragma unroll
      for(int j=0;j<4;j++) creg[m][j]=0.f;
    for(int t=0;t<TT;t++){
      if(t>0) waitarr(p.Lf, 32, t);
      dev_lstmP(As2, p, t, cb, p.h_hist + (size_t)t*SLOT, p.h_hist + (size_t)(t+1)*SLOT, creg);
      setflag(p.Lf + cb*16, t+1);
    }
  } else if(cb < 48){
    int w = cb-32;
    for(int t=0;t<TT;t++){
      waitarr(p.Lf, 32, t+1);
      int bt = p.Bt[t];
      unsigned short* S = p.sbuf + (size_t)t*7*SLOT;
      if(w<8) dev_mm1(As2, p.stb + (size_t)t*SLOT,        p.w_saff, p.sab, S,      1, w,   bt);
      else    dev_mm1(As2, p.h_hist + (size_t)(t+1)*SLOT, p.w_haff, p.hab, S+SLOT, 2, w-8, bt);
      setflag(p.SAf + w*16, t+1);
    }
  } else if(cb < 80){
    int w = cb-48;
    int q = w>>3, x0 = w&7;
    for(int t=0;t<TT;t++){
      waitarr(p.SAf, 16, t+1);
      int bt = p.Bt[t];
      unsigned short* S = p.sbuf + (size_t)t*7*SLOT;
      const unsigned short* src = (q==0||q==2) ? S : S+SLOT;
      const unsigned short* W   = (q==0)? p.w_satt : (q==1)? p.w_hatt : p.w_ctx;
      const float* bias         = (q==0)? p.stbias : (q==1)? p.htb    : nullptr;
      unsigned short* out       = S + (size_t)(2+q)*SLOT;
      dev_mm1(As2, src, W, bias, out, 0, x0, bt);
      setflag(p.SBf + w*16, t+1);
    }
  } else if(cb < 144){
    int w = cb-80;
    for(int t=0;t<TT;t++){
      waitarr(p.SBf, 32, t+1);
      int bt = p.Bt[t];
      unsigned short* S = p.sbuf + (size_t)t*7*SLOT;
      #pragma unroll
      for(int r=0;r<2;r++){
        int b = w*2+r;
        if(b < bt) dev_attn(sS,sA,sHA,sSA, b, p, S+2*SLOT, S+3*SLOT, S+4*SLOT, S+5*SLOT, S+6*SLOT);
      }
      setflag(p.S3f + w*16, t+1);
    }
  } else {
    int f = cb-144;
    for(int t=0;t<TT;t++){
      waitarr(p.S3f, 64, t+1);
      unsigned short* S = p.sbuf + (size_t)t*7*SLOT;
      dev_fcF(As2, p, t, f, S+6*SLOT);
    }
  }
}

// ---------- host launch ----------
extern "C" void kernel_launch(void* const* d_in, const int* in_sizes, int n_in,
                              void* d_out, int out_size, void* d_ws, size_t ws_size,
                              hipStream_t stream)
{
  const float* enc  =(const float*)d_in[0];
  const float* gfeat=(const float*)d_in[1];
  const int*   caps =(const int*)d_in[2];
  const int*   lens =(const int*)d_in[3];
  const float* embW =(const float*)d_in[4];
  const float* e2hW =(const float*)d_in[5];  const float* e2hb=(const float*)d_in[6];
  const float* gfW  =(const float*)d_in[7];  const float* gfb =(const float*)d_in[8];
  const float* fcW  =(const float*)d_in[9];  const float* fcb =(const float*)d_in[10];
  const float* WihF =(const float*)d_in[11]; const float* bih =(const float*)d_in[12];
  const float* WhhF =(const float*)d_in[13]; const float* bhh =(const float*)d_in[14];
  const float* xgWF =(const float*)d_in[15]; const float* bxg =(const float*)d_in[16];
  const float* hgWF =(const float*)d_in[17]; const float* bhg =(const float*)d_in[18];
  const float* saWF =(const float*)d_in[19]; const float* sab =(const float*)d_in[20];
  const float* stWF =(const float*)d_in[21]; const float* stbias=(const float*)d_in[22];
  const float* haWF =(const float*)d_in[23]; const float* hab =(const float*)d_in[24];
  const float* htWF =(const float*)d_in[25]; const float* htb =(const float*)d_in[26];
  const float* vaWF =(const float*)d_in[27]; const float* vab =(const float*)d_in[28];
  const float* alW  =(const float*)d_in[29]; const float* alb =(const float*)d_in[30];
  const float* cxWF =(const float*)d_in[31]; const float* cxb =(const float*)d_in[32];

  char* base=(char*)d_ws; size_t off=0;
  auto alloc=[&](size_t bytes)->void*{ void* r=base+off; off += (bytes+255)&~(size_t)255; return r; };

  int* order=(int*)alloc(BB*4);
  int* Bt   =(int*)alloc(32*4);
  unsigned short* w_e2h =(unsigned short*)alloc((size_t)512*2048*2);
  unsigned short* w_gf  =(unsigned short*)alloc((size_t)512*2048*2);
  unsigned short* w_fc  =(unsigned short*)alloc((size_t)VOCAB*512*2);
  unsigned short* w_ih  =(unsigned short*)alloc((size_t)2048*1024*2);
  unsigned short* w_hh  =(unsigned short*)alloc((size_t)2048*512*2);
  unsigned short* w_xg  =(unsigned short*)alloc((size_t)512*1024*2);
  unsigned short* w_hg  =(unsigned short*)alloc((size_t)512*512*2);
  unsigned short* w_saff=(unsigned short*)alloc((size_t)512*512*2);
  unsigned short* w_satt=(unsigned short*)alloc((size_t)512*512*2);
  unsigned short* w_haff=(unsigned short*)alloc((size_t)512*512*2);
  unsigned short* w_hatt=(unsigned short*)alloc((size_t)512*512*2);
  unsigned short* w_vatt=(unsigned short*)alloc((size_t)512*512*2);
  unsigned short* w_ctx =(unsigned short*)alloc((size_t)512*512*2);
  unsigned short* spatial=(unsigned short*)alloc((size_t)BB*NPIX*512*2);
  unsigned short* vattn  =(unsigned short*)alloc((size_t)BB*NPIX*512*2);
  unsigned short* SC     =(unsigned short*)alloc((size_t)BB*NPIX*512*2);
  unsigned short* gimg   =(unsigned short*)alloc((size_t)BB*512*2);
  unsigned short* xt     =(unsigned short*)alloc((size_t)BB*TT*1024*2);
  int* flags =(int*)alloc(16384);
  unsigned short* Gx  =(unsigned short*)alloc((size_t)TT*2560*128*2);
  unsigned short* sbuf=(unsigned short*)alloc((size_t)TT*7*SLOT*2);
  // fresh (never-cached) buffers for cross-block tensors — NO aliasing onto weights
  unsigned short* h_hist=(unsigned short*)alloc((size_t)(TT+1)*SLOT*2);
  unsigned short* stb_hist=(unsigned short*)alloc((size_t)TT*SLOT*2);

  k_sort<<<1,BB,0,stream>>>(lens, order, Bt);

  WC13 wc;
  const float* srcs[13] = {e2hW,gfW,fcW,WihF,WhhF,xgWF,hgWF,saWF,stWF,haWF,htWF,vaWF,cxWF};
  unsigned short* dsts[13] = {w_e2h,w_gf,w_fc,w_ih,w_hh,w_xg,w_hg,w_saff,w_satt,w_haff,w_hatt,w_vatt,w_ctx};
  int ns[13] = {512*2048,512*2048,VOCAB*512,2048*1024,2048*512,512*1024,512*512,512*512,512*512,512*512,512*512,512*512,512*512};
  for(int i=0;i<13;i++){ wc.src[i]=srcs[i]; wc.dst[i]=dsts[i]; wc.n[i]=ns[i]; }
  k_wconv<<<1024,256,0,stream>>>(wc);

  k_gemm_f32A2<<<dim3(2,NPIX),256,0,stream>>>(enc, ENCD, NPIX, order, w_e2h, e2hb, spatial, ENCD);
  k_gemm_f32A2<<<dim3(2,1),  256,0,stream>>>(gfeat, ENCD, 1, order, w_gf, gfb, gimg, ENCD);
  k_xt<<<1024,256,0,stream>>>(caps, order, embW, gimg, xt);
  {
    PreD2 dv{};
    dv.d[0] = PreD{spatial, w_vatt, vab,     vattn};
    dv.d[1] = PreD{spatial, w_ctx,  nullptr, SC};
    k_pre<<<dim3(8,NPIX,2),256,0,stream>>>(dv);
  }
  k_gx<<<dim3(40,TT),256,0,stream>>>(xt, w_ih, w_xg, bih, bhh, bxg, bhg, Gx);

  hipMemsetAsync(flags, 0, 16384, stream);

  PCtx pc;
  pc.w_hh=w_hh; pc.w_hg=w_hg; pc.Gx=Gx;
  pc.w_saff=w_saff; pc.w_satt=w_satt; pc.w_haff=w_haff; pc.w_hatt=w_hatt; pc.w_ctx=w_ctx; pc.w_fc=w_fc;
  pc.vattn=vattn; pc.SC=SC;
  pc.sab=sab; pc.stbias=stbias; pc.hab=hab; pc.htb=htb;
  pc.alW=alW; pc.alb=alb; pc.cxb=cxb; pc.fcb=fcb;
  pc.Bt=Bt;
  pc.h_hist=h_hist; pc.stb=stb_hist; pc.sbuf=sbuf;
  pc.dout=(float*)d_out;
  pc.Lf  = flags;            // 32 flags @ 64B stride
  pc.SAf = flags + 32*16;    // 16 flags
  pc.SBf = flags + 48*16;    // 32 flags
  pc.S3f = flags + 80*16;    // 64 flags

  k_persist<<<256,256,0,stream>>>(pc);
}

// Round 12
// 2655.536 us; speedup vs baseline: 3.3309x; 1.0557x over previous
//
#include <hip/hip_runtime.h>
#include <hip/hip_bf16.h>
#include <cstdint>
#include <cstddef>

#define DEVI __device__ __forceinline__

// ---------- constants ----------
#define BB 128
#define TT 30
#define VOCAB 10000
#define ENCD 2048
#define NPIX 49
#define SLOT 65536   // 128*512 elements

typedef __attribute__((ext_vector_type(8))) short bf16x8;
typedef __attribute__((ext_vector_type(4))) float f32x4;

DEVI float bf2f(unsigned short u){ union{float f; unsigned int i;} x; x.i=((unsigned)u)<<16; return x.f; }
DEVI unsigned short f2bf(float f){ union{float f; unsigned int i;} x; x.f=f; unsigned r=x.i + 0x7fffu + ((x.i>>16)&1u); return (unsigned short)(r>>16); }
DEVI float sigm(float x){ return 1.0f/(1.0f+expf(-x)); }
DEVI f32x4 mfma16(bf16x8 a, bf16x8 b, f32x4 c){ return __builtin_amdgcn_mfma_f32_16x16x32_bf16(a,b,c,0,0,0); }

// ---------- async global->LDS (16B/lane, all loads in flight, no VGPR round-trip) ----------
DEVI void gload_lds16(const void* g, void* l){
  __builtin_amdgcn_global_load_lds((const __attribute__((address_space(1))) unsigned int*)g,
                                   (__attribute__((address_space(3))) unsigned int*)l, 16, 0, 0);
}

// ---------- sync: relaxed poll (no acquire), RELEASE flag store (wbl2 pushes data to CP) ----------
DEVI void waitarr(int* base, int n, int thresh){
  __syncthreads();
  if(threadIdx.x < 64){
    for(;;){
      int v = (threadIdx.x<n) ? __hip_atomic_load(base + threadIdx.x*16, __ATOMIC_RELAXED, __HIP_MEMORY_SCOPE_AGENT)
                              : 0x7fffffff;
      if(__all(v >= thresh)) break;
      __builtin_amdgcn_s_sleep(8);
    }
  }
  asm volatile("" ::: "memory");
  __syncthreads();
}
DEVI void setflag(int* f, int val){
  __syncthreads();   // all waves' stores drained to L2
  if(threadIdx.x==0) __hip_atomic_store(f, val, __ATOMIC_RELEASE, __HIP_MEMORY_SCOPE_AGENT); // wbl2 + store
}

// ---------- sort: stable descending by length ----------
__global__ void k_sort(const int* __restrict__ lens, int* __restrict__ order, int* __restrict__ Bt){
  __shared__ int L[BB];
  int i = threadIdx.x;
  L[i] = lens[i];
  __syncthreads();
  int li = L[i]; int rank = 0;
  for(int j=0;j<BB;j++){ int lj=L[j]; rank += (lj>li) || (lj==li && j<i); }
  order[rank] = i;
  if(i<TT){ int c=0; for(int j=0;j<BB;j++) c += (L[j]>i); Bt[i]=c; }
}

// ---------- weight f32 -> bf16 conversion ----------
struct WC13 { const float* src[13]; unsigned short* dst[13]; int n[13]; };
__global__ void k_wconv(WC13 wc){
  int stride = gridDim.x*blockDim.x;
  int tid0 = blockIdx.x*blockDim.x + threadIdx.x;
  for(int s=0;s<13;s++){
    const float4* src=(const float4*)wc.src[s];
    int n4 = wc.n[s]>>2;
    ushort4* dst=(ushort4*)wc.dst[s];
    for(int i=tid0;i<n4;i+=stride){
      float4 v=src[i];
      ushort4 o; o.x=f2bf(v.x); o.y=f2bf(v.y); o.z=f2bf(v.z); o.w=f2bf(v.w);
      dst[i]=o;
    }
  }
}

// ---------- xt build ----------
__global__ void k_xt(const int* __restrict__ caps, const int* __restrict__ order,
                     const float* __restrict__ embW, const unsigned short* __restrict__ gimg,
                     unsigned short* __restrict__ xt){
  int total=BB*TT*1024;
  for(int idx=blockIdx.x*blockDim.x+threadIdx.x; idx<total; idx+=gridDim.x*blockDim.x){
    int k=idx&1023; int bt=idx>>10; int t=bt%TT; int b=bt/TT;
    unsigned short v;
    if(k<512){ int tok=caps[order[b]*TT+t]; v=f2bf(embW[(size_t)tok*512+k]); }
    else v=gimg[b*512+(k-512)];
    xt[idx]=v;
  }
}

// ---------- GEMM, f32 A row-reordered -> bf16, 256-col tiles ----------
__global__ __launch_bounds__(256) void k_gemm_f32A2(
    const float* __restrict__ A, int lda, int rpb, const int* __restrict__ order,
    const unsigned short* __restrict__ W, const float* __restrict__ bias,
    unsigned short* __restrict__ out, int K)
{
  __shared__ unsigned short As[128][136];
  int tid=threadIdx.x, wave=tid>>6, lane=tid&63, l15=lane&15, l4=lane>>4;
  int mb = blockIdx.y*128;
  f32x4 acc[8][4];
  f32x4 z = {0.f,0.f,0.f,0.f};
  #pragma unroll
  for(int i=0;i<8;i++)
    #pragma unroll
    for(int j=0;j<4;j++) acc[i][j]=z;
  int cch=tid&15, r0=tid>>4;
  int nb = blockIdx.x*256 + wave*64;
  for(int kc=0;kc<K;kc+=128){
    __syncthreads();
    #pragma unroll
    for(int rp=0;rp<8;rp++){
      int r=r0+rp*16;
      int m=mb+r;
      int sb = order[m/rpb]*rpb + m%rpb;
      const float* p = A + (size_t)sb*lda + kc + cch*8;
      float4 v0=*(const float4*)p, v1=*(const float4*)(p+4);
      unsigned short* d=&As[r][cch*8];
      d[0]=f2bf(v0.x); d[1]=f2bf(v0.y); d[2]=f2bf(v0.z); d[3]=f2bf(v0.w);
      d[4]=f2bf(v1.x); d[5]=f2bf(v1.y); d[6]=f2bf(v1.z); d[7]=f2bf(v1.w);
    }
    __syncthreads();
    #pragma unroll
    for(int kk=0;kk<4;kk++){
      bf16x8 bfr[4];
      #pragma unroll
      for(int nt=0;nt<4;nt++)
        bfr[nt] = *(const bf16x8*)(W + (size_t)(nb+nt*16+l15)*K + kc + kk*32 + l4*8);
      #pragma unroll
      for(int mt=0;mt<8;mt++){
        bf16x8 af = *(const bf16x8*)&As[mt*16+l15][kk*32+l4*8];
        #pragma unroll
        for(int nt=0;nt<4;nt++) acc[mt][nt]=mfma16(af,bfr[nt],acc[mt][nt]);
      }
    }
  }
  #pragma unroll
  for(int nt=0;nt<4;nt++){
    int n = nb + nt*16 + l15;
    float bs = bias[n];
    #pragma unroll
    for(int mt=0;mt<8;mt++){
      #pragma unroll
      for(int j=0;j<4;j++){
        int row = mb + mt*16 + l4*4 + j;
        float v = acc[mt][nt][j]+bs; v = v>0.f ? v : 0.f;
        out[(size_t)row*512 + n] = f2bf(v);
      }
    }
  }
}

// ---------- precompute GEMM (cached A) ----------
DEVI void dev_gemm512c(unsigned short (*As)[136], const unsigned short* A, const unsigned short* W,
                       const float* bias, unsigned short* out, int xtile){
  int tid=threadIdx.x, wave=tid>>6, lane=tid&63, l15=lane&15, l4=lane>>4;
  f32x4 acc[8];
  f32x4 z = {0.f,0.f,0.f,0.f};
  #pragma unroll
  for(int i=0;i<8;i++) acc[i]=z;
  int cch=tid&15, r0=tid>>4;
  int nrow = xtile*64 + wave*16 + l15;
  for(int kc=0;kc<512;kc+=128){
    __syncthreads();
    #pragma unroll
    for(int rp=0;rp<8;rp++){
      int r=r0+rp*16;
      *(uint4*)&As[r][cch*8] = *(const uint4*)(A + (size_t)r*512 + kc + cch*8);
    }
    __syncthreads();
    #pragma unroll
    for(int kk=0;kk<4;kk++){
      bf16x8 bfr = *(const bf16x8*)(W + (size_t)nrow*512 + kc + kk*32 + l4*8);
      #pragma unroll
      for(int mt=0;mt<8;mt++){
        bf16x8 af = *(const bf16x8*)&As[mt*16+l15][kk*32+l4*8];
        acc[mt]=mfma16(af,bfr,acc[mt]);
      }
    }
  }
  float bs = bias ? bias[nrow] : 0.f;
  #pragma unroll
  for(int mt=0;mt<8;mt++){
    #pragma unroll
    for(int j=0;j<4;j++){
      int row = mt*16 + l4*4 + j;
      out[(size_t)row*512+nrow]=f2bf(acc[mt][j]+bs);
    }
  }
  __syncthreads();
}

struct PreD { const unsigned short* A; const unsigned short* W; const float* bias; unsigned short* out; };
struct PreD2 { PreD d[2]; };
__global__ __launch_bounds__(256) void k_pre(PreD2 dd){
  __shared__ unsigned short As[128][136];
  PreD g = dd.d[blockIdx.z];
  dev_gemm512c(As, g.A + (size_t)blockIdx.y*128*512, g.W, g.bias,
               g.out + (size_t)blockIdx.y*128*512, blockIdx.x);
}

// ---------- G_x precompute ----------
__global__ __launch_bounds__(256) void k_gx(
    const unsigned short* __restrict__ xt, const unsigned short* __restrict__ w_ih,
    const unsigned short* __restrict__ w_xg,
    const float* __restrict__ bih, const float* __restrict__ bhh,
    const float* __restrict__ bxg, const float* __restrict__ bhg,
    unsigned short* __restrict__ Gx)
{
  __shared__ unsigned short As[128][136];
  int tid=threadIdx.x, wave=tid>>6, lane=tid&63, l15=lane&15, l4=lane>>4;
  int t = blockIdx.y;
  f32x4 acc[8];
  f32x4 z = {0.f,0.f,0.f,0.f};
  #pragma unroll
  for(int i=0;i<8;i++) acc[i]=z;
  int cch=tid&15, r0=tid>>4;
  int n = blockIdx.x*64 + wave*16 + l15;
  const unsigned short* wrow = (n<2048) ? (w_ih + (size_t)n*1024) : (w_xg + (size_t)(n-2048)*1024);
  for(int kc=0;kc<1024;kc+=128){
    __syncthreads();
    #pragma unroll
    for(int rp=0;rp<8;rp++){
      int r=r0+rp*16;
      *(uint4*)&As[r][cch*8] = *(const uint4*)(xt + (size_t)r*(TT*1024) + t*1024 + kc + cch*8);
    }
    __syncthreads();
    #pragma unroll
    for(int kk=0;kk<4;kk++){
      bf16x8 bfr = *(const bf16x8*)(wrow + kc + kk*32 + l4*8);
      #pragma unroll
      for(int mt=0;mt<8;mt++){
        bf16x8 af = *(const bf16x8*)&As[mt*16+l15][kk*32+l4*8];
        acc[mt]=mfma16(af,bfr,acc[mt]);
      }
    }
  }
  float bias = (n<2048) ? (bih[n]+bhh[n]) : (bxg[n-2048]+bhg[n-2048]);
  #pragma unroll
  for(int mt=0;mt<8;mt++){
    int row = mt*16 + l4*4;
    ushort4 o;
    o.x=f2bf(acc[mt][0]+bias); o.y=f2bf(acc[mt][1]+bias);
    o.z=f2bf(acc[mt][2]+bias); o.w=f2bf(acc[mt][3]+bias);
    *(ushort4*)(Gx + ((size_t)t*2560 + n)*128 + row) = o;
  }
}

// ---------- persistent-kernel context ----------
struct PCtx {
  const unsigned short *w_hh, *w_hg, *Gx;
  const unsigned short *w_saff, *w_satt, *w_haff, *w_hatt, *w_ctx, *w_fc;
  const unsigned short *vattn, *SC;
  const float *sab,*stbias,*hab,*htb, *alW,*alb, *cxb, *fcb;
  const int *Bt;
  unsigned short *h_hist;   // (TT+1) slots
  unsigned short *stb;      // TT slots
  unsigned short *sbuf;     // TT x 7 x SLOT (Saff,Haff,Satt,Hatt,Scs,Sch,Outl)
  float *dout;
  int *Lf,*SAf,*SBf,*S3f;   // flags at 64B stride
};

// ---------- async swizzled stage: 128x512 bf16 panel, LDS linear [128][512] ----------
// LDS row r holds h[r][c ^ ((r&7)<<3)] : lane l loads global 16B at col (l^(r&7))*8.
DEVI void stage_async(char* lds, const unsigned short* src){
  int wave = threadIdx.x>>6, lane = threadIdx.x&63;
  #pragma unroll
  for(int i=0;i<32;i++){
    int row = wave*32 + i;
    const unsigned short* g = src + (size_t)row*512 + ((lane ^ (row&7))<<3);
    gload_lds16(g, lds + row*1024 + lane*16);
  }
}
// swizzled MFMA A-fragment read: row R, element-col base cb
DEVI bf16x8 ldsA(const char* lds, int R, int cb){
  return *(const bf16x8*)(lds + R*1024 + (((unsigned)cb<<1) ^ ((unsigned)(R&7)<<4)));
}

// ---------- LSTM step (32 blocks x 16 cols), c in regs ----------
DEVI void dev_lstmP(char* lds, const PCtx& p, int t, int cb,
                    const unsigned short* hprev, unsigned short* hout, float creg[2][4]){
  int tid=threadIdx.x, wave=tid>>6, lane=tid&63, l15=lane&15, l4=lane>>4;
  int jb = cb*16;
  int bt = p.Bt[t];
  __syncthreads();
  if(t>0) stage_async(lds, hprev);   // in flight during Gx loads
  f32x4 acc[2][5];
  #pragma unroll
  for(int m=0;m<2;m++){
    #pragma unroll
    for(int s=0;s<5;s++){
      int col = (s<4) ? (s*512 + jb + l15) : (2048 + jb + l15);
      int row = (wave*2+m)*16 + l4*4;
      ushort4 g = *(const ushort4*)(p.Gx + ((size_t)t*2560 + col)*128 + row);
      acc[m][s][0]=bf2f(g.x); acc[m][s][1]=bf2f(g.y); acc[m][s][2]=bf2f(g.z); acc[m][s][3]=bf2f(g.w);
    }
  }
  __syncthreads();   // drains vmcnt incl. global_load_lds
  if(t>0){
    #pragma unroll
    for(int kk=0;kk<16;kk++){
      int kg = kk*32 + l4*8;
      bf16x8 bfr[5];
      #pragma unroll
      for(int s=0;s<5;s++){
        const unsigned short* wp = (s<4) ? (p.w_hh + (size_t)(s*512+jb+l15)*512 + kg)
                                         : (p.w_hg + (size_t)(jb+l15)*512 + kg);
        bfr[s] = *(const bf16x8*)wp;
      }
      #pragma unroll
      for(int m=0;m<2;m++){
        bf16x8 af = ldsA(lds, (wave*2+m)*16+l15, kk*32+l4*8);
        #pragma unroll
        for(int s=0;s<5;s++) acc[m][s]=mfma16(af,bfr[s],acc[m][s]);
      }
    }
  }
  int j = jb + l15;
  unsigned short* stt = p.stb + (size_t)t*SLOT;
  #pragma unroll
  for(int m=0;m<2;m++){
    int mt = wave*2+m;
    #pragma unroll
    for(int jj=0;jj<4;jj++){
      int b = mt*16 + l4*4 + jj;
      float iv = sigm(acc[m][0][jj]);
      float fv = sigm(acc[m][1][jj]);
      float gv = tanhf(acc[m][2][jj]);
      float ov = sigm(acc[m][3][jj]);
      float sv = sigm(acc[m][4][jj]);
      float cn = fv*creg[m][jj] + iv*gv;
      float tc = tanhf(cn);
      int hw = f2bf(ov*tc);
      int sw = f2bf(sv*tc);
      int hp = __shfl_xor(hw,1);
      int sp = __shfl_xor(sw,1);
      if(b<bt){
        if((l15&1)==0){
          *(unsigned*)(hout + (size_t)b*512 + j) = (unsigned)(hw&0xffff) | ((unsigned)hp<<16);
          *(unsigned*)(stt  + (size_t)b*512 + j) = (unsigned)(sw&0xffff) | ((unsigned)sp<<16);
        }
        creg[m][jj]=cn;
      }
    }
  }
}

// ---------- side GEMM: async stage, one 64-col tile, masked stores ----------
DEVI void dev_mm1(char* lds, const unsigned short* src, const unsigned short* W,
                  const float* bias, unsigned short* out, int act, int xtile, int bt){
  int tid=threadIdx.x, wave=tid>>6, lane=tid&63, l15=lane&15, l4=lane>>4;
  __syncthreads();
  stage_async(lds, src);
  __syncthreads();
  int nrow = xtile*64 + wave*16 + l15;
  f32x4 acc[8];
  f32x4 z = {0.f,0.f,0.f,0.f};
  #pragma unroll
  for(int i=0;i<8;i++) acc[i]=z;
  #pragma unroll
  for(int kk=0;kk<16;kk++){
    bf16x8 bfr = *(const bf16x8*)(W + (size_t)nrow*512 + kk*32 + l4*8);
    #pragma unroll
    for(int mt=0;mt<8;mt++){
      bf16x8 af = ldsA(lds, mt*16+l15, kk*32+l4*8);
      acc[mt]=mfma16(af,bfr,acc[mt]);
    }
  }
  float bs = bias ? bias[nrow] : 0.f;
  #pragma unroll
  for(int mt=0;mt<8;mt++){
    #pragma unroll
    for(int j=0;j<4;j++){
      float v = acc[mt][j]+bs;
      if(act==1) v = fmaxf(v,0.f);
      else if(act==2) v = tanhf(v);
      int w = f2bf(v);
      int pw = __shfl_xor(w,1);
      int row = mt*16 + l4*4 + j;
      if((l15&1)==0 && row<bt)
        *(unsigned*)(out + (size_t)row*512 + (nrow&~1)) = (unsigned)(w&0xffff) | ((unsigned)pw<<16);
    }
  }
}

// ---------- attention for one batch row (normal loads) ----------
DEVI void dev_attn(float* sS, float* sA, unsigned short* sHA, unsigned short* sSA,
                   int b, const PCtx& p,
                   const unsigned short* satt, const unsigned short* hatt,
                   const unsigned short* scs, const unsigned short* sch,
                   unsigned short* outl){
  int tid=threadIdx.x;
  if(tid<64)       *(uint4*)&sHA[tid*8] = *(const uint4*)(hatt + (size_t)b*512 + tid*8);
  else if(tid<128){ int q=tid-64; *(uint4*)&sSA[q*8] = *(const uint4*)(satt + (size_t)b*512 + q*8); }
  __syncthreads();
  int gid=tid>>4, gl=tid&15;
  #pragma unroll
  for(int rp=0;rp<4;rp++){
    int pp = rp*16 + gid;
    float s = 0.f;
    if(pp<50){
      if(pp<NPIX){
        const unsigned short* vp = p.vattn + ((size_t)b*NPIX + pp)*512;
        #pragma unroll 8
        for(int k=gl*32;k<gl*32+32;k++) s += tanhf(bf2f(vp[k]) + bf2f(sHA[k])) * p.alW[k];
      } else {
        #pragma unroll 8
        for(int k=gl*32;k<gl*32+32;k++) s += tanhf(bf2f(sSA[k]) + bf2f(sHA[k])) * p.alW[k];
      }
    }
    #pragma unroll
    for(int off=8;off>=1;off>>=1) s += __shfl_xor(s, off);
    if(gl==0 && pp<50) sS[pp] = s + p.alb[0];
  }
  __syncthreads();
  if(tid<64){
    float sv = (tid<50) ? sS[tid] : -1e30f;
    float m = sv;
    #pragma unroll
    for(int off=32;off>=1;off>>=1) m = fmaxf(m, __shfl_xor(m, off));
    float e = (tid<50) ? expf(sv-m) : 0.f;
    float sum = e;
    #pragma unroll
    for(int off=32;off>=1;off>>=1) sum += __shfl_xor(sum, off);
    if(tid<50) sA[tid] = e/sum;
  }
  __syncthreads();
  float a49 = sA[49];
  {
    int n0 = tid*2;
    unsigned schU = *(const unsigned*)(sch + (size_t)b*512 + n0);
    unsigned scsU = *(const unsigned*)(scs + (size_t)b*512 + n0);
    float c0 = bf2f((unsigned short)schU), c1 = bf2f((unsigned short)(schU>>16));
    float s0 = bf2f((unsigned short)scsU), s1 = bf2f((unsigned short)(scsU>>16));
    float acc0 = c0 + a49*s0 + p.cxb[n0];
    float acc1 = c1 + a49*s1 + p.cxb[n0+1];
    const unsigned short* sp = p.SC + (size_t)b*NPIX*512 + n0;
    #pragma unroll 7
    for(int pp=0;pp<NPIX;pp++){
      unsigned u = *(const unsigned*)(sp + (size_t)pp*512);
      acc0 += sA[pp]*bf2f((unsigned short)u);
      acc1 += sA[pp]*bf2f((unsigned short)(u>>16));
    }
    unsigned o = ((unsigned)f2bf(tanhf(acc1))<<16) | (unsigned)(f2bf(tanhf(acc0))&0xffff);
    *(unsigned*)(outl + (size_t)b*512 + n0) = o;
  }
  __syncthreads();
}

// ---------- fc: async stage outl, 1-2 tiles per block, NT logit stores ----------
DEVI void dev_fcF(char* lds, const PCtx& p, int t, int f, const unsigned short* outl){
  int tid=threadIdx.x;
  int bt = p.Bt[t];
  __syncthreads();
  stage_async(lds, outl);
  __syncthreads();
  int wave=tid>>6, lane=tid&63, l15=lane&15, l4=lane>>4;
  for(int x=f; x<157; x+=112){
    f32x4 acc[8];
    f32x4 z = {0.f,0.f,0.f,0.f};
    #pragma unroll
    for(int i=0;i<8;i++) acc[i]=z;
    int nbase = x*64 + wave*16;
    int nr = nbase + l15; if(nr > VOCAB-1) nr = VOCAB-1;
    #pragma unroll 4
    for(int kk=0;kk<16;kk++){
      bf16x8 bfr = *(const bf16x8*)(p.w_fc + (size_t)nr*512 + kk*32 + l4*8);
      #pragma unroll
      for(int mt=0;mt<8;mt++){
        if(mt*16 < bt){
          bf16x8 af = ldsA(lds, mt*16+l15, kk*32+l4*8);
          acc[mt]=mfma16(af,bfr,acc[mt]);
        }
      }
    }
    int n = nbase + l15; bool nok = n < VOCAB;
    float bs = nok ? p.fcb[n] : 0.f;
    #pragma unroll
    for(int mt=0;mt<8;mt++){
      #pragma unroll
      for(int j=0;j<4;j++){
        int b = mt*16 + l4*4 + j;
        float v = (b<bt) ? (acc[mt][j]+bs) : 0.f;
        if(nok) __builtin_nontemporal_store(v, &p.dout[(size_t)b*(TT*VOCAB) + (size_t)t*VOCAB + n]);
      }
    }
  }
}

// ---------- persistent kernel: L(0-31) SA(32-47) SB(48-79) AT(80-143) FC(144-255) ----------
__global__ __launch_bounds__(256) void k_persist(PCtx p){
  __shared__ __align__(16) char smem[133760];
  char* lds = smem;                       // linear [128][512] bf16 stage (131072 B)
  unsigned short* sHA = (unsigned short*)smem;   // attn blocks only
  unsigned short* sSA = sHA + 512;
  float* sS = (float*)(smem + 2048);
  float* sA = sS + 64;
  int cb = blockIdx.x;

  if(cb < 32){
    float creg[2][4];
    #pragma unroll
    for(int m=0;m<2;m++)
      #pragma unroll
      for(int j=0;j<4;j++) creg[m][j]=0.f;
    for(int t=0;t<TT;t++){
      if(t>0) waitarr(p.Lf, 32, t);
      dev_lstmP(lds, p, t, cb, p.h_hist + (size_t)t*SLOT, p.h_hist + (size_t)(t+1)*SLOT, creg);
      setflag(p.Lf + cb*16, t+1);
    }
  } else if(cb < 48){
    int w = cb-32;
    for(int t=0;t<TT;t++){
      waitarr(p.Lf, 32, t+1);
      int bt = p.Bt[t];
      unsigned short* S = p.sbuf + (size_t)t*7*SLOT;
      if(w<8) dev_mm1(lds, p.stb + (size_t)t*SLOT,        p.w_saff, p.sab, S,      1, w,   bt);
      else    dev_mm1(lds, p.h_hist + (size_t)(t+1)*SLOT, p.w_haff, p.hab, S+SLOT, 2, w-8, bt);
      setflag(p.SAf + w*16, t+1);
    }
  } else if(cb < 80){
    int w = cb-48;
    int q = w>>3, x0 = w&7;
    for(int t=0;t<TT;t++){
      waitarr(p.SAf, 16, t+1);
      int bt = p.Bt[t];
      unsigned short* S = p.sbuf + (size_t)t*7*SLOT;
      const unsigned short* src = (q==0||q==2) ? S : S+SLOT;
      const unsigned short* W   = (q==0)? p.w_satt : (q==1)? p.w_hatt : p.w_ctx;
      const float* bias         = (q==0)? p.stbias : (q==1)? p.htb    : nullptr;
      unsigned short* out       = S + (size_t)(2+q)*SLOT;
      dev_mm1(lds, src, W, bias, out, 0, x0, bt);
      setflag(p.SBf + w*16, t+1);
    }
  } else if(cb < 144){
    int w = cb-80;
    for(int t=0;t<TT;t++){
      waitarr(p.SBf, 32, t+1);
      int bt = p.Bt[t];
      unsigned short* S = p.sbuf + (size_t)t*7*SLOT;
      #pragma unroll
      for(int r=0;r<2;r++){
        int b = w*2+r;
        if(b < bt) dev_attn(sS,sA,sHA,sSA, b, p, S+2*SLOT, S+3*SLOT, S+4*SLOT, S+5*SLOT, S+6*SLOT);
      }
      setflag(p.S3f + w*16, t+1);
    }
  } else {
    int f = cb-144;
    for(int t=0;t<TT;t++){
      waitarr(p.S3f, 64, t+1);
      unsigned short* S = p.sbuf + (size_t)t*7*SLOT;
      dev_fcF(lds, p, t, f, S+6*SLOT);
    }
  }
}

// ---------- host launch ----------
extern "C" void kernel_launch(void* const* d_in, const int* in_sizes, int n_in,
                              void* d_out, int out_size, void* d_ws, size_t ws_size,
                              hipStream_t stream)
{
  const float* enc  =(const float*)d_in[0];
  const float* gfeat=(const float*)d_in[1];
  const int*   caps =(const int*)d_in[2];
  const int*   lens =(const int*)d_in[3];
  const float* embW =(const float*)d_in[4];
  const float* e2hW =(const float*)d_in[5];  const float* e2hb=(const float*)d_in[6];
  const float* gfW  =(const float*)d_in[7];  const float* gfb =(const float*)d_in[8];
  const float* fcW  =(const float*)d_in[9];  const float* fcb =(const float*)d_in[10];
  const float* WihF =(const float*)d_in[11]; const float* bih =(const float*)d_in[12];
  const float* WhhF =(const float*)d_in[13]; const float* bhh =(const float*)d_in[14];
  const float* xgWF =(const float*)d_in[15]; const float* bxg =(const float*)d_in[16];
  const float* hgWF =(const float*)d_in[17]; const float* bhg =(const float*)d_in[18];
  const float* saWF =(const float*)d_in[19]; const float* sab =(const float*)d_in[20];
  const float* stWF =(const float*)d_in[21]; const float* stbias=(const float*)d_in[22];
  const float* haWF =(const float*)d_in[23]; const float* hab =(const float*)d_in[24];
  const float* htWF =(const float*)d_in[25]; const float* htb =(const float*)d_in[26];
  const float* vaWF =(const float*)d_in[27]; const float* vab =(const float*)d_in[28];
  const float* alW  =(const float*)d_in[29]; const float* alb =(const float*)d_in[30];
  const float* cxWF =(const float*)d_in[31]; const float* cxb =(const float*)d_in[32];

  char* base=(char*)d_ws; size_t off=0;
  auto alloc=[&](size_t bytes)->void*{ void* r=base+off; off += (bytes+255)&~(size_t)255; return r; };

  int* order=(int*)alloc(BB*4);
  int* Bt   =(int*)alloc(32*4);
  unsigned short* w_e2h =(unsigned short*)alloc((size_t)512*2048*2);
  unsigned short* w_gf  =(unsigned short*)alloc((size_t)512*2048*2);
  unsigned short* w_fc  =(unsigned short*)alloc((size_t)VOCAB*512*2);
  unsigned short* w_ih  =(unsigned short*)alloc((size_t)2048*1024*2);
  unsigned short* w_hh  =(unsigned short*)alloc((size_t)2048*512*2);
  unsigned short* w_xg  =(unsigned short*)alloc((size_t)512*1024*2);
  unsigned short* w_hg  =(unsigned short*)alloc((size_t)512*512*2);
  unsigned short* w_saff=(unsigned short*)alloc((size_t)512*512*2);
  unsigned short* w_satt=(unsigned short*)alloc((size_t)512*512*2);
  unsigned short* w_haff=(unsigned short*)alloc((size_t)512*512*2);
  unsigned short* w_hatt=(unsigned short*)alloc((size_t)512*512*2);
  unsigned short* w_vatt=(unsigned short*)alloc((size_t)512*512*2);
  unsigned short* w_ctx =(unsigned short*)alloc((size_t)512*512*2);
  unsigned short* spatial=(unsigned short*)alloc((size_t)BB*NPIX*512*2);
  unsigned short* vattn  =(unsigned short*)alloc((size_t)BB*NPIX*512*2);
  unsigned short* SC     =(unsigned short*)alloc((size_t)BB*NPIX*512*2);
  unsigned short* gimg   =(unsigned short*)alloc((size_t)BB*512*2);
  unsigned short* xt     =(unsigned short*)alloc((size_t)BB*TT*1024*2);
  int* flags =(int*)alloc(16384);
  unsigned short* Gx  =(unsigned short*)alloc((size_t)TT*2560*128*2);
  unsigned short* sbuf=(unsigned short*)alloc((size_t)TT*7*SLOT*2);
  unsigned short* h_hist=(unsigned short*)alloc((size_t)(TT+1)*SLOT*2);
  unsigned short* stb_hist=(unsigned short*)alloc((size_t)TT*SLOT*2);

  k_sort<<<1,BB,0,stream>>>(lens, order, Bt);

  WC13 wc;
  const float* srcs[13] = {e2hW,gfW,fcW,WihF,WhhF,xgWF,hgWF,saWF,stWF,haWF,htWF,vaWF,cxWF};
  unsigned short* dsts[13] = {w_e2h,w_gf,w_fc,w_ih,w_hh,w_xg,w_hg,w_saff,w_satt,w_haff,w_hatt,w_vatt,w_ctx};
  int ns[13] = {512*2048,512*2048,VOCAB*512,2048*1024,2048*512,512*1024,512*512,512*512,512*512,512*512,512*512,512*512,512*512};
  for(int i=0;i<13;i++){ wc.src[i]=srcs[i]; wc.dst[i]=dsts[i]; wc.n[i]=ns[i]; }
  k_wconv<<<1024,256,0,stream>>>(wc);

  k_gemm_f32A2<<<dim3(2,NPIX),256,0,stream>>>(enc, ENCD, NPIX, order, w_e2h, e2hb, spatial, ENCD);
  k_gemm_f32A2<<<dim3(2,1),  256,0,stream>>>(gfeat, ENCD, 1, order, w_gf, gfb, gimg, ENCD);
  k_xt<<<1024,256,0,stream>>>(caps, order, embW, gimg, xt);
  {
    PreD2 dv{};
    dv.d[0] = PreD{spatial, w_vatt, vab,     vattn};
    dv.d[1] = PreD{spatial, w_ctx,  nullptr, SC};
    k_pre<<<dim3(8,NPIX,2),256,0,stream>>>(dv);
  }
  k_gx<<<dim3(40,TT),256,0,stream>>>(xt, w_ih, w_xg, bih, bhh, bxg, bhg, Gx);

  hipMemsetAsync(flags, 0, 16384, stream);

  PCtx pc;
  pc.w_hh=w_hh; pc.w_hg=w_hg; pc.Gx=Gx;
  pc.w_saff=w_saff; pc.w_satt=w_satt; pc.w_haff=w_haff; pc.w_hatt=w_hatt; pc.w_ctx=w_ctx; pc.w_fc=w_fc;
  pc.vattn=vattn; pc.SC=SC;
  pc.sab=sab; pc.stbias=stbias; pc.hab=hab; pc.htb=htb;
  pc.alW=alW; pc.alb=alb; pc.cxb=cxb; pc.fcb=fcb;
  pc.Bt=Bt;
  pc.h_hist=h_hist; pc.stb=stb_hist; pc.sbuf=sbuf;
  pc.dout=(float*)d_out;
  pc.Lf  = flags;            // 32 flags @ 64B stride
  pc.SAf = flags + 32*16;    // 16 flags
  pc.SBf = flags + 48*16;    // 32 flags
  pc.S3f = flags + 80*16;    // 64 flags

  k_persist<<<256,256,0,stream>>>(pc);
}